// Round 9
// baseline (350.219 us; speedup 1.0000x reference)
//
#include <hip/hip_runtime.h>
#include <math.h>

#define N_NODES 50000
#define N_PAD   50048              // rows padded to multiple of 64
#define N_EDGES 1600000
#define DIM     128
#define RCUT    5.0f
#define NGROUP  (N_PAD / 64)       // 782 groups of 64 nodes
#define NB_PRE  512
#define CH_PRE  (N_EDGES / NB_PRE) // 3125 edges per preA histogram chunk
#define NB_CONV 6250               // convert blocks in preA
#define NB_WPREP 8                 // wprep blocks in preA
#define NB_RE   128                // reorder blocks (4 preA chunks each)
#define CH_RE   (N_EDGES / NB_RE)  // 12500 edges per reorder block
#define XPAD    136                // LDS X tile row stride in bf16 (272 B)
#define NTILE   (N_PAD / 16)       // 3128 16-node tiles for layer12

typedef __attribute__((ext_vector_type(8))) __bf16 bf16x8;
typedef __attribute__((ext_vector_type(4))) float  f32x4;

// ---------------- bf16 helpers ----------------
__device__ __forceinline__ float bf_lo(unsigned int u) { return __uint_as_float(u << 16); }
__device__ __forceinline__ float bf_hi(unsigned int u) { return __uint_as_float(u & 0xffff0000u); }
__device__ __forceinline__ unsigned short f2bf(float x) {
    unsigned int u = __float_as_uint(x);
    u += 0x7fffu + ((u >> 16) & 1u);   // round-to-nearest-even
    return (unsigned short)(u >> 16);
}

// ---------------- preA: convert v->bf16  |  W->frags  |  group-64 histogram ---
__global__ __launch_bounds__(256) void preA_kernel(
        const float* __restrict__ v, unsigned short* __restrict__ vb,
        const float* __restrict__ Aw, uint4* __restrict__ wfrag,
        const int* __restrict__ dst, int* __restrict__ partial) {
    int b = blockIdx.x;
    if (b < NB_CONV) {
        int i = b * 256 + threadIdx.x;           // exactly N_NODES*DIM/4
        float4 x = ((const float4*)v)[i];
        uint2 o;
        o.x = (unsigned)f2bf(x.x) | ((unsigned)f2bf(x.y) << 16);
        o.y = (unsigned)f2bf(x.z) | ((unsigned)f2bf(x.w) << 16);
        ((uint2*)vb)[i] = o;
    } else if (b < NB_CONV + NB_WPREP) {
        int t = (b - NB_CONV) * 256 + threadIdx.x;   // 0..2047
        int lane = t & 63, nt = (t >> 6) & 7, kk = t >> 9;
        int n  = nt * 16 + (lane & 15);
        int k0 = kk * 32 + (lane >> 4) * 8;
        unsigned short h[8];
        #pragma unroll
        for (int i = 0; i < 8; ++i) h[i] = f2bf(Aw[n * DIM + k0 + i]);
        uint4 o;
        o.x = h[0] | ((unsigned)h[1] << 16); o.y = h[2] | ((unsigned)h[3] << 16);
        o.z = h[4] | ((unsigned)h[5] << 16); o.w = h[6] | ((unsigned)h[7] << 16);
        wfrag[t] = o;
    } else {
        __shared__ int h[NGROUP];                // 3.1 KB
        int cb = b - NB_CONV - NB_WPREP, tid = threadIdx.x;
        for (int g = tid; g < NGROUP; g += 256) h[g] = 0;
        __syncthreads();
        int beg = cb * CH_PRE, end = beg + CH_PRE;
        for (int i = beg + tid; i < end; i += 256)
            atomicAdd(&h[dst[i] >> 6], 1);       // LDS atomic
        __syncthreads();
        for (int g = tid; g < NGROUP; g += 256) partial[cb * NGROUP + g] = h[g];
    }
}

// ---------------- 2-level partial sums: partial4[128][g], sum64[8][g] ------
__global__ __launch_bounds__(256) void ktot2_kernel(const int* __restrict__ partial,
                                                    int* __restrict__ partial4,
                                                    int* __restrict__ sum64) {
    int gb = blockIdx.x & 3, qq = blockIdx.x >> 2;
    int g = gb * 256 + threadIdx.x;
    if (g >= NGROUP) return;
    int acc = 0;
    #pragma unroll 1
    for (int j = 0; j < 16; ++j) {
        int s4 = 0;
        #pragma unroll
        for (int c = 0; c < 4; ++c)
            s4 += partial[(qq * 64 + j * 4 + c) * NGROUP + g];
        partial4[(qq * 16 + j) * NGROUP + g] = s4;
        acc += s4;
    }
    sum64[qq * NGROUP + g] = acc;
}

// ---------------- reorder: embedded scan + self base + group-CSR scatter ---
// Each block redundantly scans the 782 group totals (sum64, L2-hot) to get
// goff, then adds its chunk prefix (sum64 supers + partial4 within super).
// Block 0 publishes goff for layer0. Scatter identical to R8.
__global__ __launch_bounds__(512) void reorder_kernel(
        const float* __restrict__ e,
        const int*   __restrict__ src,
        const int*   __restrict__ dst,
        const float* __restrict__ rs,
        const float* __restrict__ sigma,
        const int*   __restrict__ partial4,
        const int*   __restrict__ sum64,
        int*  __restrict__ goff,
        int2* __restrict__ metaT) {
    __shared__ int base[NGROUP];
    __shared__ int cnt[NGROUP];
    __shared__ int part[512];
    int b = blockIdx.x, tid = threadIdx.x;
    int q = b >> 4;                              // super-chunk (16 blocks each)
    // ---- per-block scan over group totals ----
    int i0 = tid * 2;
    int v0 = 0, v1 = 0;
    if (i0 < NGROUP) {
        #pragma unroll
        for (int qq = 0; qq < 8; ++qq) v0 += sum64[qq * NGROUP + i0];
    }
    if (i0 + 1 < NGROUP) {
        #pragma unroll
        for (int qq = 0; qq < 8; ++qq) v1 += sum64[qq * NGROUP + i0 + 1];
    }
    part[tid] = v0 + v1; __syncthreads();
    for (int d = 1; d < 512; d <<= 1) {
        int val = (tid >= d) ? part[tid - d] : 0;
        __syncthreads(); part[tid] += val; __syncthreads();
    }
    int run = (tid == 0) ? 0 : part[tid - 1];
    if (i0 < NGROUP) {
        if (b == 0) goff[i0] = run;
        int r = run;
        for (int qq = 0; qq < q; ++qq) r += sum64[qq * NGROUP + i0];
        for (int j = q * 16; j < b; ++j) r += partial4[j * NGROUP + i0];
        base[i0] = r; cnt[i0] = 0;
        int run1 = run + v0;
        if (i0 + 1 < NGROUP) {
            if (b == 0) goff[i0 + 1] = run1;
            int r1 = run1;
            for (int qq = 0; qq < q; ++qq) r1 += sum64[qq * NGROUP + i0 + 1];
            for (int j = q * 16; j < b; ++j) r1 += partial4[j * NGROUP + i0 + 1];
            base[i0 + 1] = r1; cnt[i0 + 1] = 0;
        }
    }
    if (b == 0 && tid == 0) goff[NGROUP] = N_EDGES;
    __syncthreads();
    float rsv = rs[0], sg = sigma[0];
    int beg = b * CH_RE, end = beg + CH_RE;
    for (int i = beg + tid; i < end; i += 512) {
        float r  = e[i];
        float d  = r - rsv;
        float gauss = expf(-(d * d) / (sg * sg));
        float cut   = 0.5f * cosf(r * (float)(M_PI / (double)RCUT));
        cut = (r < RCUT) ? cut : 0.0f;
        float fe = gauss * cut;
        int dn = dst[i];
        int g  = dn >> 6;
        int lr = atomicAdd(&cnt[g], 1);          // LDS atomic
        metaT[base[g] + lr] = make_int2(src[i] * (DIM * 2) | ((dn & 63) << 24),
                                        __float_as_int(fe));
    }
}

// ---------------- shared gather inner loop (4-byte meta: src16 | f.bf16) ---
#define EDGE1(mm)                                                          \
    do {                                                                   \
        unsigned rr = *(const unsigned*)(basec + (((mm) & 0xFFFFu) << 8)); \
        float ff = bf_hi(mm);                                              \
        a0 = fmaf(ff, bf_lo(rr), a0);                                      \
        a1 = fmaf(ff, bf_hi(rr), a1);                                      \
    } while (0)

__device__ __forceinline__ void gather_node(
        const unsigned* __restrict__ meta, const char* basec,
        int beg, int end, float& a0, float& a1) {
    int c = beg;
    while ((c & 3) && c < end) { unsigned m = meta[c]; EDGE1(m); ++c; }
    for (; c + 16 <= end; c += 16) {
        uint4 m0 = *(const uint4*)(meta + c);
        uint4 m1 = *(const uint4*)(meta + c + 4);
        uint4 m2 = *(const uint4*)(meta + c + 8);
        uint4 m3 = *(const uint4*)(meta + c + 12);
        unsigned r0  = *(const unsigned*)(basec + ((m0.x & 0xFFFFu) << 8));
        unsigned r1  = *(const unsigned*)(basec + ((m0.y & 0xFFFFu) << 8));
        unsigned r2  = *(const unsigned*)(basec + ((m0.z & 0xFFFFu) << 8));
        unsigned r3  = *(const unsigned*)(basec + ((m0.w & 0xFFFFu) << 8));
        unsigned r4  = *(const unsigned*)(basec + ((m1.x & 0xFFFFu) << 8));
        unsigned r5  = *(const unsigned*)(basec + ((m1.y & 0xFFFFu) << 8));
        unsigned r6  = *(const unsigned*)(basec + ((m1.z & 0xFFFFu) << 8));
        unsigned r7  = *(const unsigned*)(basec + ((m1.w & 0xFFFFu) << 8));
        unsigned r8  = *(const unsigned*)(basec + ((m2.x & 0xFFFFu) << 8));
        unsigned r9  = *(const unsigned*)(basec + ((m2.y & 0xFFFFu) << 8));
        unsigned r10 = *(const unsigned*)(basec + ((m2.z & 0xFFFFu) << 8));
        unsigned r11 = *(const unsigned*)(basec + ((m2.w & 0xFFFFu) << 8));
        unsigned r12 = *(const unsigned*)(basec + ((m3.x & 0xFFFFu) << 8));
        unsigned r13 = *(const unsigned*)(basec + ((m3.y & 0xFFFFu) << 8));
        unsigned r14 = *(const unsigned*)(basec + ((m3.z & 0xFFFFu) << 8));
        unsigned r15 = *(const unsigned*)(basec + ((m3.w & 0xFFFFu) << 8));
        a0 = fmaf(bf_hi(m0.x), bf_lo(r0), a0);  a1 = fmaf(bf_hi(m0.x), bf_hi(r0), a1);
        a0 = fmaf(bf_hi(m0.y), bf_lo(r1), a0);  a1 = fmaf(bf_hi(m0.y), bf_hi(r1), a1);
        a0 = fmaf(bf_hi(m0.z), bf_lo(r2), a0);  a1 = fmaf(bf_hi(m0.z), bf_hi(r2), a1);
        a0 = fmaf(bf_hi(m0.w), bf_lo(r3), a0);  a1 = fmaf(bf_hi(m0.w), bf_hi(r3), a1);
        a0 = fmaf(bf_hi(m1.x), bf_lo(r4), a0);  a1 = fmaf(bf_hi(m1.x), bf_hi(r4), a1);
        a0 = fmaf(bf_hi(m1.y), bf_lo(r5), a0);  a1 = fmaf(bf_hi(m1.y), bf_hi(r5), a1);
        a0 = fmaf(bf_hi(m1.z), bf_lo(r6), a0);  a1 = fmaf(bf_hi(m1.z), bf_hi(r6), a1);
        a0 = fmaf(bf_hi(m1.w), bf_lo(r7), a0);  a1 = fmaf(bf_hi(m1.w), bf_hi(r7), a1);
        a0 = fmaf(bf_hi(m2.x), bf_lo(r8), a0);  a1 = fmaf(bf_hi(m2.x), bf_hi(r8), a1);
        a0 = fmaf(bf_hi(m2.y), bf_lo(r9), a0);  a1 = fmaf(bf_hi(m2.y), bf_hi(r9), a1);
        a0 = fmaf(bf_hi(m2.z), bf_lo(r10), a0); a1 = fmaf(bf_hi(m2.z), bf_hi(r10), a1);
        a0 = fmaf(bf_hi(m2.w), bf_lo(r11), a0); a1 = fmaf(bf_hi(m2.w), bf_hi(r11), a1);
        a0 = fmaf(bf_hi(m3.x), bf_lo(r12), a0); a1 = fmaf(bf_hi(m3.x), bf_hi(r12), a1);
        a0 = fmaf(bf_hi(m3.y), bf_lo(r13), a0); a1 = fmaf(bf_hi(m3.y), bf_hi(r13), a1);
        a0 = fmaf(bf_hi(m3.z), bf_lo(r14), a0); a1 = fmaf(bf_hi(m3.z), bf_hi(r14), a1);
        a0 = fmaf(bf_hi(m3.w), bf_lo(r15), a0); a1 = fmaf(bf_hi(m3.w), bf_hi(r15), a1);
    }
    if (c + 4 <= end) {
        uint4 m0 = *(const uint4*)(meta + c);
        unsigned r0 = *(const unsigned*)(basec + ((m0.x & 0xFFFFu) << 8));
        unsigned r1 = *(const unsigned*)(basec + ((m0.y & 0xFFFFu) << 8));
        unsigned r2 = *(const unsigned*)(basec + ((m0.z & 0xFFFFu) << 8));
        unsigned r3 = *(const unsigned*)(basec + ((m0.w & 0xFFFFu) << 8));
        a0 = fmaf(bf_hi(m0.x), bf_lo(r0), a0); a1 = fmaf(bf_hi(m0.x), bf_hi(r0), a1);
        a0 = fmaf(bf_hi(m0.y), bf_lo(r1), a0); a1 = fmaf(bf_hi(m0.y), bf_hi(r1), a1);
        a0 = fmaf(bf_hi(m0.z), bf_lo(r2), a0); a1 = fmaf(bf_hi(m0.z), bf_hi(r2), a1);
        a0 = fmaf(bf_hi(m0.w), bf_lo(r3), a0); a1 = fmaf(bf_hi(m0.w), bf_hi(r3), a1);
        c += 4;
    }
    for (; c < end; ++c) { unsigned m = meta[c]; EDGE1(m); }
}

// ---------------- layer 0: tagsort (-> 4B meta) + gather + GEMM ------------
__global__ __launch_bounds__(512) void layer0_kernel(
        const unsigned short* __restrict__ cur,   // bf16 (= vb for L0)
        const unsigned short* __restrict__ vb,
        const int2*  __restrict__ metaT,          // group-CSR, tagged, fp32 f
        const int*   __restrict__ goff,
        unsigned* __restrict__ meta,              // out: node-exact 4B CSR
        int*  __restrict__ off,                   // out: node offsets
        const uint4* __restrict__ wfrag,
        const float* __restrict__ bias,
        unsigned short* __restrict__ out_bf) {
    __shared__ unsigned short xlds[64 * XPAD];    // 17408 B
    __shared__ int c64[64], b64[65], cu64[64];
    int tid = threadIdx.x;
    int wv  = tid >> 6, lane = tid & 63;
    int g   = blockIdx.x;
    int sbeg = goff[g], send = goff[g + 1];

    // ---- tagsort: 64-bin count + scan + scatter into node-exact 4B meta ----
    if (tid < 64) c64[tid] = 0;
    __syncthreads();
    for (int i = sbeg + tid; i < send; i += 512)
        atomicAdd(&c64[(metaT[i].x >> 24) & 63], 1);
    __syncthreads();
    if (tid == 0) {
        int run = 0;
        #pragma unroll
        for (int t = 0; t < 64; ++t) { b64[t] = run; cu64[t] = run; run += c64[t]; }
        b64[64] = run;
    }
    __syncthreads();
    if (tid < 64) {
        int node = g * 64 + tid;
        if (node <= N_NODES) off[node] = sbeg + b64[tid];
    }
    for (int i = sbeg + tid; i < send; i += 512) {
        int2 m = metaT[i];
        int tag = (m.x >> 24) & 63;
        int lr = atomicAdd(&cu64[tag], 1);
        meta[sbeg + lr] = (unsigned)((m.x >> 8) & 0xFFFF)
                        | ((unsigned)f2bf(__int_as_float(m.y)) << 16);
    }
    __syncthreads();   // meta writes drained; b64 stable

    // ---- gather (offsets from LDS b64) ----
    int n0 = g * 64 + wv * 8;
    int myoff = 0;
    if (lane < 9) myoff = sbeg + b64[wv * 8 + lane];
    const char* basec = (const char*)cur + lane * 4;

    #pragma unroll 1
    for (int q = 0; q < 8; ++q) {
        int nl = wv * 8 + q;
        int n  = n0 + q;
        float a0 = 0.f, a1 = 0.f;
        if (n < N_NODES) {
            unsigned vv = *(const unsigned*)((const char*)vb + (size_t)n * (DIM * 2) + lane * 4);
            a0 = bf_lo(vv); a1 = bf_hi(vv);
            int beg = __builtin_amdgcn_readlane(myoff, q);
            int end = __builtin_amdgcn_readlane(myoff, q + 1);
            gather_node(meta, basec, beg, end, a0, a1);
        }
        *(unsigned*)(xlds + nl * XPAD + lane * 2) =
            (unsigned)f2bf(a0) | ((unsigned)f2bf(a1) << 16);
    }
    __syncthreads();

    // ---- GEMM: wave wv -> rows (wv>>1)*16..+15, col-half (wv&1) ----
    int quad = lane >> 4, l16 = lane & 15;
    int rb = wv >> 1, nh = wv & 1;
    f32x4 acc[4];
    #pragma unroll
    for (int j = 0; j < 4; ++j) acc[j] = (f32x4){0.f, 0.f, 0.f, 0.f};

    const unsigned short* xp = xlds + (rb * 16 + l16) * XPAD + quad * 8;
    #pragma unroll
    for (int kk = 0; kk < 4; ++kk) {
        bf16x8 af = *(const bf16x8*)(xp + kk * 32);
        #pragma unroll
        for (int j = 0; j < 4; ++j) {
            uint4 w = wfrag[(kk * 8 + nh * 4 + j) * 64 + lane];
            bf16x8 bfr = __builtin_bit_cast(bf16x8, w);
            acc[j] = __builtin_amdgcn_mfma_f32_16x16x32_bf16(af, bfr, acc[j], 0, 0, 0);
        }
    }

    int orow0 = g * 64 + rb * 16 + quad * 4;
    #pragma unroll
    for (int j = 0; j < 4; ++j) {
        int col = (nh * 4 + j) * 16 + l16;
        float b = bias[col];
        #pragma unroll
        for (int r = 0; r < 4; ++r) {
            int orow = orow0 + r;
            if (orow < N_NODES)
                out_bf[(size_t)orow * DIM + col] = f2bf(fmaxf(acc[j][r] + b, 0.f));
        }
    }
}

// ---------------- layers 1/2: 2-wave 16-node fused gather+GEMM -------------
__global__ __launch_bounds__(128, 8) void layer12_kernel(
        const unsigned short* __restrict__ cur,
        const unsigned short* __restrict__ vb,
        const unsigned* __restrict__ meta,
        const int*   __restrict__ off,
        const uint4* __restrict__ wfrag,
        const float* __restrict__ bias,
        unsigned short* __restrict__ out_bf,
        float* __restrict__ out_f,
        int last) {
    __shared__ unsigned short xlds[16 * XPAD];    // 4352 B
    int tid = threadIdx.x;
    int wv  = tid >> 6, lane = tid & 63;          // wv in {0,1}
    int tile = blockIdx.x;
    int n0  = tile * 16 + wv * 8;

    int offidx = n0 + ((lane < 9) ? lane : 8);
    if (offidx > N_NODES) offidx = N_NODES;
    int myoff = off[offidx];
    const char* basec = (const char*)cur + lane * 4;

    #pragma unroll 1
    for (int q = 0; q < 8; ++q) {
        int nl = wv * 8 + q;
        int n  = n0 + q;
        float a0 = 0.f, a1 = 0.f;
        if (n < N_NODES) {
            unsigned vv = *(const unsigned*)((const char*)vb + (size_t)n * (DIM * 2) + lane * 4);
            a0 = bf_lo(vv); a1 = bf_hi(vv);
            int beg = __builtin_amdgcn_readlane(myoff, q);
            int end = __builtin_amdgcn_readlane(myoff, q + 1);
            gather_node(meta, basec, beg, end, a0, a1);
        }
        *(unsigned*)(xlds + nl * XPAD + lane * 2) =
            (unsigned)f2bf(a0) | ((unsigned)f2bf(a1) << 16);
    }
    __syncthreads();

    // ---- GEMM: both waves cover all 16 rows; wave = col-half ----
    int quad = lane >> 4, l16 = lane & 15;
    f32x4 acc[4];
    #pragma unroll
    for (int j = 0; j < 4; ++j) acc[j] = (f32x4){0.f, 0.f, 0.f, 0.f};

    const unsigned short* xp = xlds + l16 * XPAD + quad * 8;
    #pragma unroll
    for (int kk = 0; kk < 4; ++kk) {
        bf16x8 af = *(const bf16x8*)(xp + kk * 32);
        #pragma unroll
        for (int j = 0; j < 4; ++j) {
            uint4 w = wfrag[(kk * 8 + wv * 4 + j) * 64 + lane];
            bf16x8 bfr = __builtin_bit_cast(bf16x8, w);
            acc[j] = __builtin_amdgcn_mfma_f32_16x16x32_bf16(af, bfr, acc[j], 0, 0, 0);
        }
    }

    int orow0 = tile * 16 + quad * 4;
    #pragma unroll
    for (int j = 0; j < 4; ++j) {
        int col = (wv * 4 + j) * 16 + l16;
        float b = bias[col];
        #pragma unroll
        for (int r = 0; r < 4; ++r) {
            int orow = orow0 + r;
            if (orow < N_NODES) {
                float val = fmaxf(acc[j][r] + b, 0.f);
                if (last) out_f[(size_t)orow * DIM + col] = val;
                else      out_bf[(size_t)orow * DIM + col] = f2bf(val);
            }
        }
    }
}

// ---------------------------------------------------------------------------
extern "C" void kernel_launch(void* const* d_in, const int* in_sizes, int n_in,
                              void* d_out, int out_size, void* d_ws, size_t ws_size,
                              hipStream_t stream) {
    const float* v     = (const float*)d_in[0];
    const float* e     = (const float*)d_in[1];
    const int*   src   = (const int*)  d_in[2];
    const int*   dst   = (const int*)  d_in[3];
    const float* Aw    = (const float*)d_in[4];
    const float* Ab    = (const float*)d_in[5];
    const float* rs    = (const float*)d_in[6];
    const float* sigma = (const float*)d_in[7];
    float* out = (float*)d_out;

    // ---- workspace layout (~45 MB used) ----
    char* p = (char*)d_ws;
    unsigned*       meta  = (unsigned*)p;        p += (size_t)N_EDGES * 8;       // 6.4 MB used (4B CSR)
    unsigned short* bufV  = (unsigned short*)p;  p += (size_t)N_PAD * DIM * 2;   // 12.81 MB (pristine bf16 v)
    unsigned short* bufA  = (unsigned short*)p;  p += (size_t)N_PAD * DIM * 2;   // 12.81 MB (metaT / L1 out)
    unsigned short* bufB  = (unsigned short*)p;  p += (size_t)N_PAD * DIM * 2;   // 12.81 MB (partials / L0 out)
    uint4*          wfrag = (uint4*)p;           p += 2048 * 16;                 //  32 KB
    int*            off   = (int*)p;             p += (size_t)(N_NODES + 2) * 4;
    int*            goff  = (int*)p;             p += (NGROUP + 2) * 4;
    // aliases (dead before host buffer's first real write):
    int2* metaT    = (int2*)bufA;                // unsorted group-CSR, dead after layer0
    int*  partial  = (int*)bufB;                 // [512][NGROUP] = 1.6 MB
    int*  partial4 = partial + NB_PRE * NGROUP;  // [128][NGROUP] = 400 KB
    int*  sum64    = partial4 + 128 * NGROUP;    // [8][NGROUP]   =  25 KB

    preA_kernel<<<NB_CONV + NB_WPREP + NB_PRE, 256, 0, stream>>>(
        v, bufV, Aw, wfrag, dst, partial);
    ktot2_kernel<<<32, 256, 0, stream>>>(partial, partial4, sum64);
    reorder_kernel<<<NB_RE, 512, 0, stream>>>(
        e, src, dst, rs, sigma, partial4, sum64, goff, metaT);

    // L0: tagsort + gather(bufV) + gemm -> bufB   (consumes metaT in bufA)
    layer0_kernel<<<NGROUP, 512, 0, stream>>>(
        bufV, bufV, metaT, goff, meta, off, wfrag, Ab, bufB);
    // L1: gather(bufB) + gemm -> bufA
    layer12_kernel<<<NTILE, 128, 0, stream>>>(
        bufB, bufV, meta, off, wfrag, Ab, bufA, nullptr, 0);
    // L2: gather(bufA) + gemm -> out (fp32)
    layer12_kernel<<<NTILE, 128, 0, stream>>>(
        bufA, bufV, meta, off, wfrag, Ab, nullptr, out, 1);
}

// Round 10
// 346.896 us; speedup vs baseline: 1.0096x; 1.0096x over previous
//
#include <hip/hip_runtime.h>
#include <math.h>

#define N_NODES 50000
#define N_PAD   50048              // rows padded to multiple of 64
#define N_EDGES 1600000
#define DIM     128
#define RCUT    5.0f
#define NGROUP  (N_PAD / 64)       // 782 groups of 64 nodes
#define NB_PRE  512
#define CH_PRE  (N_EDGES / NB_PRE) // 3125 edges per preA histogram chunk
#define NB_CONV 6250               // convert blocks in preA
#define NB_WPREP 8                 // wprep blocks in preA
#define NB_RE   128                // reorder blocks (4 preA chunks each)
#define CH_RE   (N_EDGES / NB_RE)  // 12500 edges per reorder block
#define XPAD    136                // LDS X tile row stride in bf16 (272 B)
#define NTILE   (N_PAD / 16)       // 3128 16-node tiles for layer12

typedef __attribute__((ext_vector_type(8))) __bf16 bf16x8;
typedef __attribute__((ext_vector_type(4))) float  f32x4;

// ---------------- bf16 helpers ----------------
__device__ __forceinline__ float bf_lo(unsigned int u) { return __uint_as_float(u << 16); }
__device__ __forceinline__ float bf_hi(unsigned int u) { return __uint_as_float(u & 0xffff0000u); }
__device__ __forceinline__ unsigned short f2bf(float x) {
    unsigned int u = __float_as_uint(x);
    u += 0x7fffu + ((u >> 16) & 1u);   // round-to-nearest-even
    return (unsigned short)(u >> 16);
}

// ---------------- preA: convert v->bf16  |  W->frags  |  group-64 histogram ---
__global__ __launch_bounds__(256) void preA_kernel(
        const float* __restrict__ v, unsigned short* __restrict__ vb,
        const float* __restrict__ Aw, uint4* __restrict__ wfrag,
        const int* __restrict__ dst, int* __restrict__ partial) {
    int b = blockIdx.x;
    if (b < NB_CONV) {
        int i = b * 256 + threadIdx.x;           // exactly N_NODES*DIM/4
        float4 x = ((const float4*)v)[i];
        uint2 o;
        o.x = (unsigned)f2bf(x.x) | ((unsigned)f2bf(x.y) << 16);
        o.y = (unsigned)f2bf(x.z) | ((unsigned)f2bf(x.w) << 16);
        ((uint2*)vb)[i] = o;
    } else if (b < NB_CONV + NB_WPREP) {
        int t = (b - NB_CONV) * 256 + threadIdx.x;   // 0..2047
        int lane = t & 63, nt = (t >> 6) & 7, kk = t >> 9;
        int n  = nt * 16 + (lane & 15);
        int k0 = kk * 32 + (lane >> 4) * 8;
        unsigned short h[8];
        #pragma unroll
        for (int i = 0; i < 8; ++i) h[i] = f2bf(Aw[n * DIM + k0 + i]);
        uint4 o;
        o.x = h[0] | ((unsigned)h[1] << 16); o.y = h[2] | ((unsigned)h[3] << 16);
        o.z = h[4] | ((unsigned)h[5] << 16); o.w = h[6] | ((unsigned)h[7] << 16);
        wfrag[t] = o;
    } else {
        __shared__ int h[NGROUP];                // 3.1 KB
        int cb = b - NB_CONV - NB_WPREP, tid = threadIdx.x;
        for (int g = tid; g < NGROUP; g += 256) h[g] = 0;
        __syncthreads();
        int beg = cb * CH_PRE, end = beg + CH_PRE;
        for (int i = beg + tid; i < end; i += 256)
            atomicAdd(&h[dst[i] >> 6], 1);       // LDS atomic
        __syncthreads();
        for (int g = tid; g < NGROUP; g += 256) partial[cb * NGROUP + g] = h[g];
    }
}

// ---------------- ktot2': TRANSPOSED hierarchy partial4T[g][128], sum64T[g][8]
// Block (gb,qq) writes partial4T[g][qq*16..+15] -- one full 64B line per g.
__global__ __launch_bounds__(256) void ktot2t_kernel(const int* __restrict__ partial,
                                                     int* __restrict__ partial4T,
                                                     int* __restrict__ sum64T) {
    int gb = blockIdx.x & 3, qq = blockIdx.x >> 2;
    int g = gb * 256 + threadIdx.x;
    if (g >= NGROUP) return;
    int acc = 0;
    int loc[16];
    #pragma unroll 1
    for (int j = 0; j < 16; ++j) {
        int s4 = 0;
        #pragma unroll
        for (int c = 0; c < 4; ++c)
            s4 += partial[(qq * 64 + j * 4 + c) * NGROUP + g];
        loc[j] = s4;
        acc += s4;
    }
    #pragma unroll
    for (int j = 0; j < 16; ++j) partial4T[g * 128 + qq * 16 + j] = loc[j];
    sum64T[g * 8 + qq] = acc;
}

// ---------------- reorder: embedded scan + contiguous self-base + scatter --
// Block b covers preA chunks 4b..4b+3. goff via per-block scan of sum64T
// (contiguous 32B/group); base prefix via partial4T[g][0..b) (contiguous).
__global__ __launch_bounds__(512) void reorder_kernel(
        const float* __restrict__ e,
        const int*   __restrict__ src,
        const int*   __restrict__ dst,
        const float* __restrict__ rs,
        const float* __restrict__ sigma,
        const int*   __restrict__ partial4T,
        const int*   __restrict__ sum64T,
        int*  __restrict__ goff,
        int2* __restrict__ metaT) {
    __shared__ int base[NGROUP];
    __shared__ int cnt[NGROUP];
    __shared__ int part[512];
    int b = blockIdx.x, tid = threadIdx.x;
    // ---- per-block scan over group totals (contiguous sum64T rows) ----
    int i0 = tid * 2;
    int v0 = 0, v1 = 0;
    if (i0 < NGROUP) {
        #pragma unroll
        for (int qq = 0; qq < 8; ++qq) v0 += sum64T[i0 * 8 + qq];
    }
    if (i0 + 1 < NGROUP) {
        #pragma unroll
        for (int qq = 0; qq < 8; ++qq) v1 += sum64T[(i0 + 1) * 8 + qq];
    }
    part[tid] = v0 + v1; __syncthreads();
    for (int d = 1; d < 512; d <<= 1) {
        int val = (tid >= d) ? part[tid - d] : 0;
        __syncthreads(); part[tid] += val; __syncthreads();
    }
    int run = (tid == 0) ? 0 : part[tid - 1];
    if (i0 < NGROUP) {
        if (b == 0) goff[i0] = run;
        int r = run;
        #pragma unroll 4
        for (int j = 0; j < b; ++j) r += partial4T[i0 * 128 + j];   // contiguous
        base[i0] = r; cnt[i0] = 0;
        int run1 = run + v0;
        if (i0 + 1 < NGROUP) {
            if (b == 0) goff[i0 + 1] = run1;
            int r1 = run1;
            #pragma unroll 4
            for (int j = 0; j < b; ++j) r1 += partial4T[(i0 + 1) * 128 + j];
            base[i0 + 1] = r1; cnt[i0 + 1] = 0;
        }
    }
    if (b == 0 && tid == 0) goff[NGROUP] = N_EDGES;
    __syncthreads();
    float rsv = rs[0], sg = sigma[0];
    int beg = b * CH_RE, end = beg + CH_RE;
    for (int i = beg + tid; i < end; i += 512) {
        float r  = e[i];
        float d  = r - rsv;
        float gauss = expf(-(d * d) / (sg * sg));
        float cut   = 0.5f * cosf(r * (float)(M_PI / (double)RCUT));
        cut = (r < RCUT) ? cut : 0.0f;
        float fe = gauss * cut;
        int dn = dst[i];
        int g  = dn >> 6;
        int lr = atomicAdd(&cnt[g], 1);          // LDS atomic
        metaT[base[g] + lr] = make_int2(src[i] * (DIM * 2) | ((dn & 63) << 24),
                                        __float_as_int(fe));
    }
}

// ---------------- shared gather inner loop (int2 meta, R4-proven) ----------
#define EDGE2(mx, mf, rr)                                        \
    do {                                                         \
        float ff = __int_as_float(mf);                           \
        a0 = fmaf(ff, bf_lo(rr), a0);                            \
        a1 = fmaf(ff, bf_hi(rr), a1);                            \
    } while (0)

__device__ __forceinline__ void gather_node(
        const int2* __restrict__ meta, const char* basec,
        int beg, int end, float& a0, float& a1) {
    int c = beg;
    if ((c & 1) && c < end) {
        int2 m = meta[c];
        unsigned rr = *(const unsigned*)(basec + (unsigned)m.x);
        EDGE2(m.x, m.y, rr);
        ++c;
    }
    for (; c + 16 <= end; c += 16) {
        int4 m0 = *(const int4*)(meta + c);
        int4 m1 = *(const int4*)(meta + c + 2);
        int4 m2 = *(const int4*)(meta + c + 4);
        int4 m3 = *(const int4*)(meta + c + 6);
        int4 m4 = *(const int4*)(meta + c + 8);
        int4 m5 = *(const int4*)(meta + c + 10);
        int4 m6 = *(const int4*)(meta + c + 12);
        int4 m7 = *(const int4*)(meta + c + 14);
        unsigned r0  = *(const unsigned*)(basec + (unsigned)m0.x);
        unsigned r1  = *(const unsigned*)(basec + (unsigned)m0.z);
        unsigned r2  = *(const unsigned*)(basec + (unsigned)m1.x);
        unsigned r3  = *(const unsigned*)(basec + (unsigned)m1.z);
        unsigned r4  = *(const unsigned*)(basec + (unsigned)m2.x);
        unsigned r5  = *(const unsigned*)(basec + (unsigned)m2.z);
        unsigned r6  = *(const unsigned*)(basec + (unsigned)m3.x);
        unsigned r7  = *(const unsigned*)(basec + (unsigned)m3.z);
        unsigned r8  = *(const unsigned*)(basec + (unsigned)m4.x);
        unsigned r9  = *(const unsigned*)(basec + (unsigned)m4.z);
        unsigned r10 = *(const unsigned*)(basec + (unsigned)m5.x);
        unsigned r11 = *(const unsigned*)(basec + (unsigned)m5.z);
        unsigned r12 = *(const unsigned*)(basec + (unsigned)m6.x);
        unsigned r13 = *(const unsigned*)(basec + (unsigned)m6.z);
        unsigned r14 = *(const unsigned*)(basec + (unsigned)m7.x);
        unsigned r15 = *(const unsigned*)(basec + (unsigned)m7.z);
        EDGE2(m0.x, m0.y, r0);  EDGE2(m0.z, m0.w, r1);
        EDGE2(m1.x, m1.y, r2);  EDGE2(m1.z, m1.w, r3);
        EDGE2(m2.x, m2.y, r4);  EDGE2(m2.z, m2.w, r5);
        EDGE2(m3.x, m3.y, r6);  EDGE2(m3.z, m3.w, r7);
        EDGE2(m4.x, m4.y, r8);  EDGE2(m4.z, m4.w, r9);
        EDGE2(m5.x, m5.y, r10); EDGE2(m5.z, m5.w, r11);
        EDGE2(m6.x, m6.y, r12); EDGE2(m6.z, m6.w, r13);
        EDGE2(m7.x, m7.y, r14); EDGE2(m7.z, m7.w, r15);
    }
    if (c + 8 <= end) {
        int4 m0 = *(const int4*)(meta + c);
        int4 m1 = *(const int4*)(meta + c + 2);
        int4 m2 = *(const int4*)(meta + c + 4);
        int4 m3 = *(const int4*)(meta + c + 6);
        unsigned r0 = *(const unsigned*)(basec + (unsigned)m0.x);
        unsigned r1 = *(const unsigned*)(basec + (unsigned)m0.z);
        unsigned r2 = *(const unsigned*)(basec + (unsigned)m1.x);
        unsigned r3 = *(const unsigned*)(basec + (unsigned)m1.z);
        unsigned r4 = *(const unsigned*)(basec + (unsigned)m2.x);
        unsigned r5 = *(const unsigned*)(basec + (unsigned)m2.z);
        unsigned r6 = *(const unsigned*)(basec + (unsigned)m3.x);
        unsigned r7 = *(const unsigned*)(basec + (unsigned)m3.z);
        EDGE2(m0.x, m0.y, r0); EDGE2(m0.z, m0.w, r1);
        EDGE2(m1.x, m1.y, r2); EDGE2(m1.z, m1.w, r3);
        EDGE2(m2.x, m2.y, r4); EDGE2(m2.z, m2.w, r5);
        EDGE2(m3.x, m3.y, r6); EDGE2(m3.z, m3.w, r7);
        c += 8;
    }
    for (; c < end; ++c) {
        int2 m = meta[c];
        unsigned rr = *(const unsigned*)(basec + (unsigned)m.x);
        EDGE2(m.x, m.y, rr);
    }
}

// ---------------- layer 0: tagsort + gather + GEMM (R4 verbatim) -----------
__global__ __launch_bounds__(512) void layer0_kernel(
        const unsigned short* __restrict__ cur,   // bf16 (= vb for L0)
        const unsigned short* __restrict__ vb,
        const int2*  __restrict__ metaT,          // group-CSR, tagged
        const int*   __restrict__ goff,
        int2* __restrict__ meta,                  // out: node-exact CSR
        int*  __restrict__ off,                   // out: node offsets
        const uint4* __restrict__ wfrag,
        const float* __restrict__ bias,
        unsigned short* __restrict__ out_bf) {
    __shared__ unsigned short xlds[64 * XPAD];    // 17408 B
    __shared__ int c64[64], b64[65], cu64[64];
    int tid = threadIdx.x;
    int wv  = tid >> 6, lane = tid & 63;
    int g   = blockIdx.x;
    int sbeg = goff[g], send = goff[g + 1];

    // ---- tagsort: 64-bin count + scan + scatter into node-exact meta ----
    if (tid < 64) c64[tid] = 0;
    __syncthreads();
    for (int i = sbeg + tid; i < send; i += 512)
        atomicAdd(&c64[(metaT[i].x >> 24) & 63], 1);
    __syncthreads();
    if (tid == 0) {
        int run = 0;
        #pragma unroll
        for (int t = 0; t < 64; ++t) { b64[t] = run; cu64[t] = run; run += c64[t]; }
        b64[64] = run;
    }
    __syncthreads();
    if (tid < 64) {
        int node = g * 64 + tid;
        if (node <= N_NODES) off[node] = sbeg + b64[tid];
    }
    for (int i = sbeg + tid; i < send; i += 512) {
        int2 m = metaT[i];
        int tag = (m.x >> 24) & 63;
        int lr = atomicAdd(&cu64[tag], 1);
        meta[sbeg + lr] = make_int2(m.x & 0x00FFFFFF, m.y);
    }
    __syncthreads();   // meta writes drained; b64 stable

    // ---- gather (offsets from LDS b64) ----
    int n0 = g * 64 + wv * 8;
    int myoff = 0;
    if (lane < 9) myoff = sbeg + b64[wv * 8 + lane];
    const char* basec = (const char*)cur + lane * 4;

    #pragma unroll 1
    for (int q = 0; q < 8; ++q) {
        int nl = wv * 8 + q;
        int n  = n0 + q;
        float a0 = 0.f, a1 = 0.f;
        if (n < N_NODES) {
            unsigned vv = *(const unsigned*)((const char*)vb + (size_t)n * (DIM * 2) + lane * 4);
            a0 = bf_lo(vv); a1 = bf_hi(vv);
            int beg = __builtin_amdgcn_readlane(myoff, q);
            int end = __builtin_amdgcn_readlane(myoff, q + 1);
            gather_node(meta, basec, beg, end, a0, a1);
        }
        *(unsigned*)(xlds + nl * XPAD + lane * 2) =
            (unsigned)f2bf(a0) | ((unsigned)f2bf(a1) << 16);
    }
    __syncthreads();

    // ---- GEMM: wave wv -> rows (wv>>1)*16..+15, col-half (wv&1) ----
    int quad = lane >> 4, l16 = lane & 15;
    int rb = wv >> 1, nh = wv & 1;
    f32x4 acc[4];
    #pragma unroll
    for (int j = 0; j < 4; ++j) acc[j] = (f32x4){0.f, 0.f, 0.f, 0.f};

    const unsigned short* xp = xlds + (rb * 16 + l16) * XPAD + quad * 8;
    #pragma unroll
    for (int kk = 0; kk < 4; ++kk) {
        bf16x8 af = *(const bf16x8*)(xp + kk * 32);
        #pragma unroll
        for (int j = 0; j < 4; ++j) {
            uint4 w = wfrag[(kk * 8 + nh * 4 + j) * 64 + lane];
            bf16x8 bfr = __builtin_bit_cast(bf16x8, w);
            acc[j] = __builtin_amdgcn_mfma_f32_16x16x32_bf16(af, bfr, acc[j], 0, 0, 0);
        }
    }

    int orow0 = g * 64 + rb * 16 + quad * 4;
    #pragma unroll
    for (int j = 0; j < 4; ++j) {
        int col = (nh * 4 + j) * 16 + l16;
        float b = bias[col];
        #pragma unroll
        for (int r = 0; r < 4; ++r) {
            int orow = orow0 + r;
            if (orow < N_NODES)
                out_bf[(size_t)orow * DIM + col] = f2bf(fmaxf(acc[j][r] + b, 0.f));
        }
    }
}

// ---------------- layers 1/2: 2-wave 16-node fused gather+GEMM (R4) --------
__global__ __launch_bounds__(128, 8) void layer12_kernel(
        const unsigned short* __restrict__ cur,
        const unsigned short* __restrict__ vb,
        const int2*  __restrict__ meta,
        const int*   __restrict__ off,
        const uint4* __restrict__ wfrag,
        const float* __restrict__ bias,
        unsigned short* __restrict__ out_bf,
        float* __restrict__ out_f,
        int last) {
    __shared__ unsigned short xlds[16 * XPAD];    // 4352 B
    int tid = threadIdx.x;
    int wv  = tid >> 6, lane = tid & 63;          // wv in {0,1}
    int tile = blockIdx.x;
    int n0  = tile * 16 + wv * 8;

    int offidx = n0 + ((lane < 9) ? lane : 8);
    if (offidx > N_NODES) offidx = N_NODES;
    int myoff = off[offidx];
    const char* basec = (const char*)cur + lane * 4;

    #pragma unroll 1
    for (int q = 0; q < 8; ++q) {
        int nl = wv * 8 + q;
        int n  = n0 + q;
        float a0 = 0.f, a1 = 0.f;
        if (n < N_NODES) {
            unsigned vv = *(const unsigned*)((const char*)vb + (size_t)n * (DIM * 2) + lane * 4);
            a0 = bf_lo(vv); a1 = bf_hi(vv);
            int beg = __builtin_amdgcn_readlane(myoff, q);
            int end = __builtin_amdgcn_readlane(myoff, q + 1);
            gather_node(meta, basec, beg, end, a0, a1);
        }
        *(unsigned*)(xlds + nl * XPAD + lane * 2) =
            (unsigned)f2bf(a0) | ((unsigned)f2bf(a1) << 16);
    }
    __syncthreads();

    // ---- GEMM: both waves cover all 16 rows; wave = col-half ----
    int quad = lane >> 4, l16 = lane & 15;
    f32x4 acc[4];
    #pragma unroll
    for (int j = 0; j < 4; ++j) acc[j] = (f32x4){0.f, 0.f, 0.f, 0.f};

    const unsigned short* xp = xlds + l16 * XPAD + quad * 8;
    #pragma unroll
    for (int kk = 0; kk < 4; ++kk) {
        bf16x8 af = *(const bf16x8*)(xp + kk * 32);
        #pragma unroll
        for (int j = 0; j < 4; ++j) {
            uint4 w = wfrag[(kk * 8 + wv * 4 + j) * 64 + lane];
            bf16x8 bfr = __builtin_bit_cast(bf16x8, w);
            acc[j] = __builtin_amdgcn_mfma_f32_16x16x32_bf16(af, bfr, acc[j], 0, 0, 0);
        }
    }

    int orow0 = tile * 16 + quad * 4;
    #pragma unroll
    for (int j = 0; j < 4; ++j) {
        int col = (wv * 4 + j) * 16 + l16;
        float b = bias[col];
        #pragma unroll
        for (int r = 0; r < 4; ++r) {
            int orow = orow0 + r;
            if (orow < N_NODES) {
                float val = fmaxf(acc[j][r] + b, 0.f);
                if (last) out_f[(size_t)orow * DIM + col] = val;
                else      out_bf[(size_t)orow * DIM + col] = f2bf(val);
            }
        }
    }
}

// ---------------------------------------------------------------------------
extern "C" void kernel_launch(void* const* d_in, const int* in_sizes, int n_in,
                              void* d_out, int out_size, void* d_ws, size_t ws_size,
                              hipStream_t stream) {
    const float* v     = (const float*)d_in[0];
    const float* e     = (const float*)d_in[1];
    const int*   src   = (const int*)  d_in[2];
    const int*   dst   = (const int*)  d_in[3];
    const float* Aw    = (const float*)d_in[4];
    const float* Ab    = (const float*)d_in[5];
    const float* rs    = (const float*)d_in[6];
    const float* sigma = (const float*)d_in[7];
    float* out = (float*)d_out;

    // ---- workspace layout (~51.5 MB) ----
    char* p = (char*)d_ws;
    int2*           meta  = (int2*)p;            p += (size_t)N_EDGES * 8;       // 12.8 MB (final CSR)
    unsigned short* bufV  = (unsigned short*)p;  p += (size_t)N_PAD * DIM * 2;   // 12.81 MB (pristine bf16 v)
    unsigned short* bufA  = (unsigned short*)p;  p += (size_t)N_PAD * DIM * 2;   // 12.81 MB (metaT / L1 out)
    unsigned short* bufB  = (unsigned short*)p;  p += (size_t)N_PAD * DIM * 2;   // 12.81 MB (partials / L0 out)
    uint4*          wfrag = (uint4*)p;           p += 2048 * 16;                 //  32 KB
    int*            off   = (int*)p;             p += (size_t)(N_NODES + 2) * 4;
    int*            goff  = (int*)p;             p += (NGROUP + 2) * 4;
    // aliases (dead before host buffer's first real write):
    int2* metaT     = (int2*)bufA;               // unsorted group-CSR, dead after layer0
    int*  partial   = (int*)bufB;                // [512][NGROUP] = 1.6 MB
    int*  partial4T = partial + NB_PRE * NGROUP; // [NGROUP][128] = 400 KB (transposed)
    int*  sum64T    = partial4T + NGROUP * 128;  // [NGROUP][8]   =  25 KB (transposed)

    preA_kernel<<<NB_CONV + NB_WPREP + NB_PRE, 256, 0, stream>>>(
        v, bufV, Aw, wfrag, dst, partial);
    ktot2t_kernel<<<32, 256, 0, stream>>>(partial, partial4T, sum64T);
    reorder_kernel<<<NB_RE, 512, 0, stream>>>(
        e, src, dst, rs, sigma, partial4T, sum64T, goff, metaT);

    // L0: tagsort + gather(bufV) + gemm -> bufB   (consumes metaT in bufA)
    layer0_kernel<<<NGROUP, 512, 0, stream>>>(
        bufV, bufV, metaT, goff, meta, off, wfrag, Ab, bufB);
    // L1: gather(bufB) + gemm -> bufA
    layer12_kernel<<<NTILE, 128, 0, stream>>>(
        bufB, bufV, meta, off, wfrag, Ab, bufA, nullptr, 0);
    // L2: gather(bufA) + gemm -> out (fp32)
    layer12_kernel<<<NTILE, 128, 0, stream>>>(
        bufA, bufV, meta, off, wfrag, Ab, nullptr, out, 1);
}